// Round 15
// baseline (954.201 us; speedup 1.0000x reference)
//
#include <hip/hip_runtime.h>

typedef unsigned short u16;
typedef unsigned int u32;
typedef __bf16 bf16x8 __attribute__((ext_vector_type(8)));
typedef float f32x4 __attribute__((ext_vector_type(4)));

// ---------- helpers ----------
__device__ __forceinline__ u16 bf16_rne(float f) {
  u32 u = __float_as_uint(f);
  u += 0x7fffu + ((u >> 16) & 1u);
  return (u16)(u >> 16);
}
__device__ __forceinline__ float bf16_to_f(u16 h) {
  return __uint_as_float(((u32)h) << 16);
}
__device__ __forceinline__ void gload16(const u16* g, u16* l) {
  __builtin_amdgcn_global_load_lds(
      (const __attribute__((address_space(1))) void*)g,
      (__attribute__((address_space(3))) void*)l, 16, 0, 0);
}

// ---------- split fp32 -> bf16 hi (+ optional lo residual) ----------
__global__ __launch_bounds__(256) void split_kernel(const float* __restrict__ x,
                                                    u16* __restrict__ hi,
                                                    u16* __restrict__ lo, int n8) {
  int i = blockIdx.x * 256 + threadIdx.x;
  if (i >= n8) return;
  float4 a = ((const float4*)x)[2 * i];
  float4 b = ((const float4*)x)[2 * i + 1];
  float v[8] = {a.x, a.y, a.z, a.w, b.x, b.y, b.z, b.w};
  union { u16 u[8]; uint4 q; } H, L;
#pragma unroll
  for (int j = 0; j < 8; ++j) H.u[j] = bf16_rne(v[j]);
  ((uint4*)hi)[i] = H.q;
  if (lo != nullptr) {
#pragma unroll
    for (int j = 0; j < 8; ++j) L.u[j] = bf16_rne(v[j] - bf16_to_f(H.u[j]));
    ((uint4*)lo)[i] = L.q;
  }
}

// ---------- transpose 1024x1024 fp32 -> transposed bf16 hi/lo ----------
__global__ __launch_bounds__(256) void transpose_split(const float* __restrict__ in,
                                                       u16* __restrict__ hiT,
                                                       u16* __restrict__ loT) {
  __shared__ float tile[32][33];
  const int t = threadIdx.x;
  const int r0 = blockIdx.y * 32, c0 = blockIdx.x * 32;
  const int x = t & 31, y = t >> 5;  // y in 0..7
#pragma unroll
  for (int i = 0; i < 4; ++i)
    tile[y + i * 8][x] = in[(size_t)(r0 + y + i * 8) * 1024 + c0 + x];
  __syncthreads();
#pragma unroll
  for (int i = 0; i < 4; ++i) {
    float v = tile[x][y + i * 8];
    u16 h = bf16_rne(v);
    u16 l = bf16_rne(v - bf16_to_f(h));
    size_t o = (size_t)(c0 + y + i * 8) * 1024 + r0 + x;
    hiT[o] = h;
    loT[o] = l;
  }
}

// ---------- zero a 1024-float vector ----------
__global__ __launch_bounds__(256) void zero_vec(float* __restrict__ h) {
  h[blockIdx.x * 256 + threadIdx.x] = 0.f;
}

// ---------- h[d] += sum_{e in block} W[e][d] * b[e]  (64 blocks, atomics) ----------
__global__ __launch_bounds__(256) void colvec_kernel(const float* __restrict__ W,
                                                     const float* __restrict__ b,
                                                     float* __restrict__ h) {
  __shared__ float sb[16];
  const int t = threadIdx.x;
  const int e0 = blockIdx.x * 16;
  if (t < 16) sb[t] = b[e0 + t];
  __syncthreads();
  float a0 = 0.f, a1 = 0.f, a2 = 0.f, a3 = 0.f;
#pragma unroll
  for (int i = 0; i < 16; ++i) {
    const float* row = W + (size_t)(e0 + i) * 1024;
    const float be = sb[i];
    a0 += row[t] * be;
    a1 += row[t + 256] * be;
    a2 += row[t + 512] * be;
    a3 += row[t + 768] * be;
  }
  atomicAdd(&h[t], a0);
  atomicAdd(&h[t + 256], a1);
  atomicAdd(&h[t + 512], a2);
  atomicAdd(&h[t + 768], a3);
}

// ---------- w[i] = X[i,:] . h   (one wave per row) ----------
__global__ __launch_bounds__(256) void rowdot_kernel(const float* __restrict__ X,
                                                     const float* __restrict__ h,
                                                     float* __restrict__ w) {
  const int t = threadIdx.x, lane = t & 63, wv = t >> 6;
  const size_t row = (size_t)blockIdx.x * 4 + wv;
  const float4* xr = (const float4*)(X + row * 1024);
  const float4* hr = (const float4*)h;
  float acc = 0.f;
#pragma unroll
  for (int j = 0; j < 4; ++j) {
    float4 a = xr[lane + j * 64];
    float4 b = hr[lane + j * 64];
    acc += a.x * b.x + a.y * b.y + a.z * b.z + a.w * b.w;
  }
#pragma unroll
  for (int o = 32; o > 0; o >>= 1) acc += __shfl_xor(acc, o, 64);
  if (lane == 0) w[row] = acc;
}

// ---------- legacy 128x128 B^T GEMM (kept for the tiny Mt product) ----------
template <int NPROD, int EPI>
__global__ __launch_bounds__(256) void gemm_bt(
    const u16* __restrict__ Ah, const u16* __restrict__ Al,
    const u16* __restrict__ Bh, const u16* __restrict__ Bl,
    const float* __restrict__ bias,
    u16* __restrict__ Ch, u16* __restrict__ Cl,
    float* __restrict__ Cf, float scale, int K,
    int lda, int ldb, int ldc,
    long long batchA, long long batchB, long long batchC) {
  __shared__ u16 sAh[4096];
  __shared__ u16 sBh[4096];
  __shared__ u16 sAl[NPROD == 3 ? 4096 : 64];
  __shared__ u16 sBl[NPROD == 3 ? 4096 : 64];

  const int t = threadIdx.x;
  const int w = t >> 6;
  const int lane = t & 63;
  const int m0 = blockIdx.y * 128;
  const int n0 = blockIdx.x * 128;
  const long long z = blockIdx.z;

  Ah += z * batchA;
  Bh += z * batchB;

  const int rS = t >> 2;
  const int cS = (((t & 3) ^ ((t >> 3) & 3))) * 8;
  const u16* pAh = Ah + (size_t)(m0 + rS) * lda + cS;
  const u16* pBh = Bh + (size_t)(n0 + rS) * ldb + cS;
  const u16* pAl = nullptr;
  const u16* pBl = nullptr;
  if constexpr (NPROD == 3) {
    pAl = Al + z * batchA + (size_t)(m0 + rS) * lda + cS;
    pBl = Bl + z * batchB + (size_t)(n0 + rS) * ldb + cS;
  }

  const int wr = (w >> 1) * 64;
  const int wc = (w & 1) * 64;
  const int fr = lane & 15;
  const int cc = lane >> 4;
  const int fk = (cc ^ ((fr >> 1) & 3)) * 8;

  f32x4 acc[4][4];
#pragma unroll
  for (int i = 0; i < 4; ++i)
#pragma unroll
    for (int j = 0; j < 4; ++j) acc[i][j] = (f32x4){0.f, 0.f, 0.f, 0.f};

  for (int k0 = 0; k0 < K; k0 += 32) {
    __syncthreads();
#pragma unroll
    for (int j = 0; j < 2; ++j) {
      gload16(pAh + (size_t)j * 64 * lda + k0, &sAh[j * 2048 + w * 512]);
      gload16(pBh + (size_t)j * 64 * ldb + k0, &sBh[j * 2048 + w * 512]);
      if constexpr (NPROD == 3) {
        gload16(pAl + (size_t)j * 64 * lda + k0, &sAl[j * 2048 + w * 512]);
        gload16(pBl + (size_t)j * 64 * ldb + k0, &sBl[j * 2048 + w * 512]);
      }
    }
    __syncthreads();
    bf16x8 ah[4], bh[4], al[4], bl[4];
#pragma unroll
    for (int i = 0; i < 4; ++i) {
      ah[i] = *(const bf16x8*)&sAh[(wr + i * 16 + fr) * 32 + fk];
      bh[i] = *(const bf16x8*)&sBh[(wc + i * 16 + fr) * 32 + fk];
      if constexpr (NPROD == 3) {
        al[i] = *(const bf16x8*)&sAl[(wr + i * 16 + fr) * 32 + fk];
        bl[i] = *(const bf16x8*)&sBl[(wc + i * 16 + fr) * 32 + fk];
      }
    }
#pragma unroll
    for (int i = 0; i < 4; ++i)
#pragma unroll
      for (int j = 0; j < 4; ++j) {
        acc[i][j] = __builtin_amdgcn_mfma_f32_16x16x32_bf16(ah[i], bh[j], acc[i][j], 0, 0, 0);
        if constexpr (NPROD == 3) {
          acc[i][j] = __builtin_amdgcn_mfma_f32_16x16x32_bf16(ah[i], bl[j], acc[i][j], 0, 0, 0);
          acc[i][j] = __builtin_amdgcn_mfma_f32_16x16x32_bf16(al[i], bh[j], acc[i][j], 0, 0, 0);
        }
      }
  }

  if constexpr (EPI >= 2) Cf += z * batchC;

#pragma unroll
  for (int i = 0; i < 4; ++i) {
    const int row0 = m0 + wr + i * 16 + ((lane >> 4) << 2);
#pragma unroll
    for (int j = 0; j < 4; ++j) {
      const int col = n0 + wc + j * 16 + (lane & 15);
      if constexpr (EPI == 0) {
        const float b = bias ? bias[col] : 0.0f;
#pragma unroll
        for (int r = 0; r < 4; ++r) {
          float c = acc[i][j][r] + b;
          u16 h = bf16_rne(c);
          u16 l = bf16_rne(c - bf16_to_f(h));
          size_t o = (size_t)(row0 + r) * ldc + col;
          Ch[o] = h;
          Cl[o] = l;
        }
      } else if constexpr (EPI == 1) {
        const float b = bias[col];
        ushort4 pk;
        pk.x = bf16_rne(acc[i][j][0] + b);
        pk.y = bf16_rne(acc[i][j][1] + b);
        pk.z = bf16_rne(acc[i][j][2] + b);
        pk.w = bf16_rne(acc[i][j][3] + b);
        const int bb = row0 >> 11;
        const int s = row0 & 2047;
        *(ushort4*)&Ch[(size_t)bb * 2097152 + (size_t)col * 2048 + s] = pk;
      } else if constexpr (EPI == 2) {
#pragma unroll
        for (int r = 0; r < 4; ++r)
          Cf[(size_t)(row0 + r) * ldc + col] = acc[i][j][r] * scale;
      } else {
        const float wv = bias[(size_t)z * 2048 + col];
#pragma unroll
        for (int r = 0; r < 4; ++r)
          Cf[(size_t)(row0 + r) * ldc + col] = (acc[i][j][r] + wv) * scale;
      }
    }
  }
}

// ---------- 128x128 double-buffered B^T GEMM, 2+ blocks/CU ----------
// Desync strategy: LDS = 64 KB (NPROD=3) -> 2 independent blocks per CU
// (NPROD=1: 32 KB -> 4-5 blocks/CU). The two blocks' barrier groups are
// unsynchronized, so one block's LDS-read burst overlaps the other block's
// MFMA burst (m114 mechanism) without any intra-block scheduling. Skeleton
// is the proven counted-vmcnt loop: stage-next -> vmcnt(8|4) counted (next
// tile's loads stay in flight; never drains to 0 in-loop) -> barrier A ->
// frag reads + 48 MFMA (compiler-scheduled lgkm) -> lgkmcnt(0) -> barrier B.
// XCD-aware bijective blockIdx swizzle for L2 locality.
template <int NPROD, int EPI>
__global__ __launch_bounds__(256) void gemm128(
    const u16* __restrict__ Ah, const u16* __restrict__ Al,
    const u16* __restrict__ Bh, const u16* __restrict__ Bl,
    const float* __restrict__ bias,
    u16* __restrict__ Ch, u16* __restrict__ Cl,
    float* __restrict__ Cf, float scale, int K,
    int lda, int ldb, int ldc,
    long long batchA, long long batchB, long long batchC) {
  __shared__ u16 sAh[8192];
  __shared__ u16 sBh[8192];
  __shared__ u16 sAl[NPROD == 3 ? 8192 : 8];
  __shared__ u16 sBl[NPROD == 3 ? 8192 : 8];

  const int t = threadIdx.x;
  const int w = t >> 6;     // wave 0..3
  const int lane = t & 63;

  // XCD-aware bijective swizzle (all gemm128 grids have total % 8 == 0)
  const u32 gx = gridDim.x;
  const u32 gxy = gridDim.x * gridDim.y;
  const u32 total = gxy * gridDim.z;
  const u32 h = blockIdx.x + gridDim.x * (blockIdx.y + gridDim.y * blockIdx.z);
  const u32 l = (h & 7) * (total >> 3) + (h >> 3);
  const u32 bz = l / gxy;
  const u32 rem = l - bz * gxy;
  const u32 by = rem / gx;
  const u32 bx = rem - by * gx;
  const int m0 = by * 128;
  const int n0 = bx * 128;
  const long long z = bz;

  const int rS = t >> 2;                            // staging row 0..63
  const int cS = (((t & 3) ^ ((t >> 3) & 3))) * 8;  // swizzled source chunk
  const u16* pAh = Ah + z * batchA + (size_t)(m0 + rS) * lda + cS;
  const u16* pBh = Bh + z * batchB + (size_t)(n0 + rS) * ldb + cS;
  const u16* pAl = nullptr;
  const u16* pBl = nullptr;
  if constexpr (NPROD == 3) {
    pAl = Al + z * batchA + (size_t)(m0 + rS) * lda + cS;
    pBl = Bl + z * batchB + (size_t)(n0 + rS) * ldb + cS;
  }

  const int wr = (w >> 1) * 64;
  const int wc = (w & 1) * 64;
  const int fr = lane & 15;
  const int cc = lane >> 4;
  const int fk = (cc ^ ((fr >> 1) & 3)) * 8;

  f32x4 acc[4][4];
#pragma unroll
  for (int i = 0; i < 4; ++i)
#pragma unroll
    for (int j = 0; j < 4; ++j) acc[i][j] = (f32x4){0.f, 0.f, 0.f, 0.f};

  // stage one 128x32 tile of each array into buffer at elem offset bo
  auto STAGE = [&](int bo, int k0) {
#pragma unroll
    for (int j = 0; j < 2; ++j) {
      gload16(pAh + (size_t)j * 64 * lda + k0, &sAh[bo + j * 2048 + w * 512]);
      gload16(pBh + (size_t)j * 64 * ldb + k0, &sBh[bo + j * 2048 + w * 512]);
      if constexpr (NPROD == 3) {
        gload16(pAl + (size_t)j * 64 * lda + k0, &sAl[bo + j * 2048 + w * 512]);
        gload16(pBl + (size_t)j * 64 * ldb + k0, &sBl[bo + j * 2048 + w * 512]);
      }
    }
  };

  // prologue: stage tile 0 (retired by first in-loop counted vmcnt)
  STAGE(0, 0);

  const int nt = K >> 5;
  for (int kt = 0; kt < nt; ++kt) {
    const int bc = (kt & 1) * 4096;   // current buffer elem offset
    const int bn = 4096 - bc;         // next buffer
    const bool pf = (kt + 1) < nt;

    // stage tile kt+1 (its destination buffer's readers retired at the
    // previous iteration's lgkm(0)+barrier B)
    if (pf) STAGE(bn, (kt + 1) << 5);
    __builtin_amdgcn_sched_barrier(0);
    // counted wait: tile kt's loads retired; tile kt+1's stay in flight
    if (pf) {
      if constexpr (NPROD == 3)
        asm volatile("s_waitcnt vmcnt(8)" ::: "memory");
      else
        asm volatile("s_waitcnt vmcnt(4)" ::: "memory");
    } else {
      asm volatile("s_waitcnt vmcnt(0)" ::: "memory");
    }
    __builtin_amdgcn_sched_barrier(0);
    asm volatile("s_barrier" ::: "memory");  // barrier A: tile kt visible

    bf16x8 ah[4], bh[4], al[4], bl[4];
#pragma unroll
    for (int i = 0; i < 4; ++i) {
      ah[i] = *(const bf16x8*)&sAh[bc + (wr + i * 16 + fr) * 32 + fk];
      bh[i] = *(const bf16x8*)&sBh[bc + (wc + i * 16 + fr) * 32 + fk];
      if constexpr (NPROD == 3) {
        al[i] = *(const bf16x8*)&sAl[bc + (wr + i * 16 + fr) * 32 + fk];
        bl[i] = *(const bf16x8*)&sBl[bc + (wc + i * 16 + fr) * 32 + fk];
      }
    }
    __builtin_amdgcn_s_setprio(1);
#pragma unroll
    for (int i = 0; i < 4; ++i)
#pragma unroll
      for (int j = 0; j < 4; ++j) {
        acc[i][j] = __builtin_amdgcn_mfma_f32_16x16x32_bf16(ah[i], bh[j], acc[i][j], 0, 0, 0);
        if constexpr (NPROD == 3) {
          acc[i][j] = __builtin_amdgcn_mfma_f32_16x16x32_bf16(ah[i], bl[j], acc[i][j], 0, 0, 0);
          acc[i][j] = __builtin_amdgcn_mfma_f32_16x16x32_bf16(al[i], bh[j], acc[i][j], 0, 0, 0);
        }
      }
    __builtin_amdgcn_s_setprio(0);
    __builtin_amdgcn_sched_barrier(0);
    // barrier B: all waves' reads of buf[bc] retired -> next iteration may
    // overwrite it. lgkm(0) only (no vmcnt: staged loads stay in flight).
    asm volatile("s_waitcnt lgkmcnt(0)" ::: "memory");
    asm volatile("s_barrier" ::: "memory");
  }

  if constexpr (EPI >= 2) Cf += z * batchC;

#pragma unroll
  for (int i = 0; i < 4; ++i) {
    const int row0 = m0 + wr + i * 16 + ((lane >> 4) << 2);
#pragma unroll
    for (int j = 0; j < 4; ++j) {
      const int col = n0 + wc + j * 16 + (lane & 15);
      if constexpr (EPI == 0) {
        const float bsv = bias ? bias[col] : 0.0f;
#pragma unroll
        for (int r = 0; r < 4; ++r) {
          float c = acc[i][j][r] + bsv;
          u16 hh = bf16_rne(c);
          u16 ll = bf16_rne(c - bf16_to_f(hh));
          size_t o = (size_t)(row0 + r) * ldc + col;
          Ch[o] = hh;
          Cl[o] = ll;
        }
      } else if constexpr (EPI == 1) {
        const float bsv = bias[col];
        ushort4 pk;
        pk.x = bf16_rne(acc[i][j][0] + bsv);
        pk.y = bf16_rne(acc[i][j][1] + bsv);
        pk.z = bf16_rne(acc[i][j][2] + bsv);
        pk.w = bf16_rne(acc[i][j][3] + bsv);
        const int bb = row0 >> 11;
        const int s = row0 & 2047;
        *(ushort4*)&Ch[(size_t)bb * 2097152 + (size_t)col * 2048 + s] = pk;
      } else if constexpr (EPI == 2) {
#pragma unroll
        for (int r = 0; r < 4; ++r)
          Cf[(size_t)(row0 + r) * ldc + col] = acc[i][j][r] * scale;
      } else {  // EPI == 3
        const float wv = bias[(size_t)z * 2048 + col];
#pragma unroll
        for (int r = 0; r < 4; ++r)
          Cf[(size_t)(row0 + r) * ldc + col] = (acc[i][j][r] + wv) * scale;
      }
    }
  }
}

// ---------- row softmax: in-place fp32 + bf16 copy ----------
__global__ __launch_bounds__(256) void softmax_kernel(float* __restrict__ L,
                                                      u16* __restrict__ P) {
  const size_t row = blockIdx.x;
  float* r = L + row * 2048;
  u16* p = P + row * 2048;
  const int t = threadIdx.x;
  const int w = t >> 6;
  const int lane = t & 63;

  float4 v0 = ((const float4*)r)[2 * t];
  float4 v1 = ((const float4*)r)[2 * t + 1];
  float e[8] = {v0.x, v0.y, v0.z, v0.w, v1.x, v1.y, v1.z, v1.w};

  float vm = e[0];
#pragma unroll
  for (int j = 1; j < 8; ++j) vm = fmaxf(vm, e[j]);
#pragma unroll
  for (int o = 32; o > 0; o >>= 1) vm = fmaxf(vm, __shfl_xor(vm, o, 64));
  __shared__ float redm[4], reds[4];
  if (lane == 0) redm[w] = vm;
  __syncthreads();
  vm = fmaxf(fmaxf(redm[0], redm[1]), fmaxf(redm[2], redm[3]));

  float s = 0.f;
#pragma unroll
  for (int j = 0; j < 8; ++j) {
    e[j] = __expf(e[j] - vm);
    s += e[j];
  }
#pragma unroll
  for (int o = 32; o > 0; o >>= 1) s += __shfl_xor(s, o, 64);
  if (lane == 0) reds[w] = s;
  __syncthreads();
  s = reds[0] + reds[1] + reds[2] + reds[3];
  const float inv = 1.0f / s;

  float4 o0, o1;
  o0.x = e[0] * inv; o0.y = e[1] * inv; o0.z = e[2] * inv; o0.w = e[3] * inv;
  o1.x = e[4] * inv; o1.y = e[5] * inv; o1.z = e[6] * inv; o1.w = e[7] * inv;
  ((float4*)r)[2 * t] = o0;
  ((float4*)r)[2 * t + 1] = o1;
  union { u16 u[8]; uint4 q; } pk;
  pk.u[0] = bf16_rne(o0.x); pk.u[1] = bf16_rne(o0.y);
  pk.u[2] = bf16_rne(o0.z); pk.u[3] = bf16_rne(o0.w);
  pk.u[4] = bf16_rne(o1.x); pk.u[5] = bf16_rne(o1.y);
  pk.u[6] = bf16_rne(o1.z); pk.u[7] = bf16_rne(o1.w);
  ((uint4*)p)[t] = pk.q;
}

extern "C" void kernel_launch(void* const* d_in, const int* in_sizes, int n_in,
                              void* d_out, int out_size, void* d_ws, size_t ws_size,
                              hipStream_t stream) {
  const float* Xq = (const float*)d_in[0];
  const float* Xk = (const float*)d_in[1];
  const float* Xv = (const float*)d_in[2];
  const float* Wq = (const float*)d_in[3];
  const float* bq = (const float*)d_in[4];
  const float* Wk = (const float*)d_in[5];
  const float* bk = (const float*)d_in[6];  // unused: row-constant in logits, softmax-invariant
  const float* Wv = (const float*)d_in[7];
  const float* bv = (const float*)d_in[8];
  (void)bk;

  char* out = (char*)d_out;
  char* ws = (char*)d_ws;

  u16* T_hi = (u16*)(out + 0);
  u16* T_lo = (u16*)(out + 33554432);
  u16* Xq_hi = (u16*)(out + 67108864);
  u16* Xq_lo = (u16*)(out + 100663296);
  u16* Xv_hi = (u16*)(out + 134217728);
  u16* Mt_hi = (u16*)(out + 167772160);
  u16* Mt_lo = (u16*)(out + 171966464);
  float* logits = (float*)(out + 67108864);
  float* outO = (float*)(out + 0);

  u16* WqT_hi = (u16*)(ws + 0);
  u16* WqT_lo = (u16*)(ws + 2097152);
  u16* WkT_hi = (u16*)(ws + 4194304);
  u16* WkT_lo = (u16*)(ws + 6291456);
  u16* Wv_hi = (u16*)(ws + 8388608);
  u16* P = (u16*)(ws + 0);
  float* hvec = (float*)(ws + 67108864);
  float* wvec = (float*)(ws + 67112960);
  u16* Xk_hi = (u16*)(ws + 67178496);
  u16* Xk_lo = (u16*)(ws + 100732928);
  u16* Vt = (u16*)(ws + 134287360);

  // 1) weight transforms
  transpose_split<<<dim3(32, 32), 256, 0, stream>>>(Wq, WqT_hi, WqT_lo);
  transpose_split<<<dim3(32, 32), 256, 0, stream>>>(Wk, WkT_hi, WkT_lo);
  zero_vec<<<4, 256, 0, stream>>>(hvec);
  colvec_kernel<<<64, 256, 0, stream>>>(Wk, bq, hvec);  // h = Wk^T bq
  split_kernel<<<512, 256, 0, stream>>>(Wv, Wv_hi, nullptr, 131072);

  // 2) input splits + w
  split_kernel<<<8192, 256, 0, stream>>>(Xk, Xk_hi, Xk_lo, 2097152);
  rowdot_kernel<<<4096, 256, 0, stream>>>(Xk, hvec, wvec);  // w = Xk h
  split_kernel<<<8192, 256, 0, stream>>>(Xq, Xq_hi, Xq_lo, 2097152);
  split_kernel<<<8192, 256, 0, stream>>>(Xv, Xv_hi, nullptr, 2097152);

  // 3) Mt = Wk^T Wq (tiny; legacy kernel)
  gemm_bt<3, 0><<<dim3(8, 8, 1), 256, 0, stream>>>(
      WkT_hi, WkT_lo, WqT_hi, WqT_lo, nullptr, Mt_hi, Mt_lo, nullptr, 1.f,
      1024, 1024, 1024, 1024, 0, 0, 0);
  // 4) v = Xv @ Wv^T + bv -> Vt[b][d][s]  (32 KB LDS -> 4-5 blocks/CU)
  gemm128<1, 1><<<dim3(8, 128, 1), 256, 0, stream>>>(
      Xv_hi, nullptr, Wv_hi, nullptr, bv, Vt, nullptr, nullptr, 1.f,
      1024, 1024, 1024, 1024, 0, 0, 0);
  // 5) T = Xq @ M -> hi/lo in d_out[0,64M)  (64 KB LDS -> 2 blocks/CU)
  gemm128<3, 0><<<dim3(8, 128, 1), 256, 0, stream>>>(
      Xq_hi, Xq_lo, Mt_hi, Mt_lo, nullptr, T_hi, T_lo, nullptr, 1.f,
      1024, 1024, 1024, 1024, 0, 0, 0);
  // 6) logits = 10*(T @ Xk^T + w_j) per batch
  gemm128<3, 3><<<dim3(16, 16, 8), 256, 0, stream>>>(
      T_hi, T_lo, Xk_hi, Xk_lo, wvec, nullptr, nullptr, logits, 10.f,
      1024, 1024, 1024, 2048, 2048LL * 1024, 2048LL * 1024, 2048LL * 2048);
  // 7) softmax in-place, bf16 copy to P
  softmax_kernel<<<16384, 256, 0, stream>>>(logits, P);
  // 8) out = P @ V per batch
  gemm128<1, 2><<<dim3(8, 16, 8), 256, 0, stream>>>(
      P, nullptr, Vt, nullptr, nullptr, nullptr, nullptr, outO, 1.f,
      2048, 2048, 2048, 1024, 2048LL * 2048, 1024LL * 2048, 2048LL * 1024);
}

// Round 17
// 871.651 us; speedup vs baseline: 1.0947x; 1.0947x over previous
//
#include <hip/hip_runtime.h>

typedef unsigned short u16;
typedef unsigned int u32;
typedef __bf16 bf16x8 __attribute__((ext_vector_type(8)));
typedef float f32x4 __attribute__((ext_vector_type(4)));

// ---------- helpers ----------
__device__ __forceinline__ u16 bf16_rne(float f) {
  u32 u = __float_as_uint(f);
  u += 0x7fffu + ((u >> 16) & 1u);
  return (u16)(u >> 16);
}
__device__ __forceinline__ float bf16_to_f(u16 h) {
  return __uint_as_float(((u32)h) << 16);
}
__device__ __forceinline__ void gload16(const u16* g, u16* l) {
  __builtin_amdgcn_global_load_lds(
      (const __attribute__((address_space(1))) void*)g,
      (__attribute__((address_space(3))) void*)l, 16, 0, 0);
}

// ---------- split fp32 -> bf16 hi (+ optional lo residual) ----------
__global__ __launch_bounds__(256) void split_kernel(const float* __restrict__ x,
                                                    u16* __restrict__ hi,
                                                    u16* __restrict__ lo, int n8) {
  int i = blockIdx.x * 256 + threadIdx.x;
  if (i >= n8) return;
  float4 a = ((const float4*)x)[2 * i];
  float4 b = ((const float4*)x)[2 * i + 1];
  float v[8] = {a.x, a.y, a.z, a.w, b.x, b.y, b.z, b.w};
  union { u16 u[8]; uint4 q; } H, L;
#pragma unroll
  for (int j = 0; j < 8; ++j) H.u[j] = bf16_rne(v[j]);
  ((uint4*)hi)[i] = H.q;
  if (lo != nullptr) {
#pragma unroll
    for (int j = 0; j < 8; ++j) L.u[j] = bf16_rne(v[j] - bf16_to_f(H.u[j]));
    ((uint4*)lo)[i] = L.q;
  }
}

// ---------- merged split for Xq (hi+lo) and Xv (hi only) ----------
__global__ __launch_bounds__(256) void split2_kernel(const float* __restrict__ x0,
                                                     u16* __restrict__ hi0,
                                                     u16* __restrict__ lo0,
                                                     const float* __restrict__ x1,
                                                     u16* __restrict__ hi1) {
  int i = blockIdx.x * 256 + threadIdx.x;
  const float* x = blockIdx.z ? x1 : x0;
  u16* hi = blockIdx.z ? hi1 : hi0;
  float4 a = ((const float4*)x)[2 * i];
  float4 b = ((const float4*)x)[2 * i + 1];
  float v[8] = {a.x, a.y, a.z, a.w, b.x, b.y, b.z, b.w};
  union { u16 u[8]; uint4 q; } H, L;
#pragma unroll
  for (int j = 0; j < 8; ++j) H.u[j] = bf16_rne(v[j]);
  ((uint4*)hi)[i] = H.q;
  if (blockIdx.z == 0) {
#pragma unroll
    for (int j = 0; j < 8; ++j) L.u[j] = bf16_rne(v[j] - bf16_to_f(H.u[j]));
    ((uint4*)lo0)[i] = L.q;
  }
}

// ---------- fused Xk split (hi/lo) + w[row] = Xk[row,:].h  ----------
// 4096 blocks x 256 threads; wave wv handles row 4*blockIdx+wv.
// Each lane: two 8-elem chunks at elem offsets 8*lane and 512+8*lane.
__global__ __launch_bounds__(256) void splitk_rowdot(const float* __restrict__ X,
                                                     const float* __restrict__ h,
                                                     u16* __restrict__ hi,
                                                     u16* __restrict__ lo,
                                                     float* __restrict__ w) {
  const int t = threadIdx.x, lane = t & 63, wv = t >> 6;
  const size_t row = (size_t)blockIdx.x * 4 + wv;
  const float* xr = X + row * 1024;
  const float4* hf = (const float4*)h;
  float acc = 0.f;
#pragma unroll
  for (int half = 0; half < 2; ++half) {
    const int e0 = half * 512 + lane * 8;
    float4 a = *(const float4*)&xr[e0];
    float4 b = *(const float4*)&xr[e0 + 4];
    float4 ha = hf[e0 >> 2];
    float4 hb = hf[(e0 >> 2) + 1];
    acc += a.x * ha.x + a.y * ha.y + a.z * ha.z + a.w * ha.w +
           b.x * hb.x + b.y * hb.y + b.z * hb.z + b.w * hb.w;
    float v[8] = {a.x, a.y, a.z, a.w, b.x, b.y, b.z, b.w};
    union { u16 u[8]; uint4 q; } H, L;
#pragma unroll
    for (int j = 0; j < 8; ++j) {
      H.u[j] = bf16_rne(v[j]);
      L.u[j] = bf16_rne(v[j] - bf16_to_f(H.u[j]));
    }
    const size_t ci = (row * 1024 + e0) >> 3;
    ((uint4*)hi)[ci] = H.q;
    ((uint4*)lo)[ci] = L.q;
  }
#pragma unroll
  for (int o = 32; o > 0; o >>= 1) acc += __shfl_xor(acc, o, 64);
  if (lane == 0) w[row] = acc;
}

// ---------- merged transpose 1024x1024 fp32 -> transposed bf16 hi/lo (x2) --
__global__ __launch_bounds__(256) void transpose_split2(
    const float* __restrict__ in0, u16* __restrict__ hiT0, u16* __restrict__ loT0,
    const float* __restrict__ in1, u16* __restrict__ hiT1, u16* __restrict__ loT1) {
  __shared__ float tile[32][33];
  const float* in = blockIdx.z ? in1 : in0;
  u16* hiT = blockIdx.z ? hiT1 : hiT0;
  u16* loT = blockIdx.z ? loT1 : loT0;
  const int t = threadIdx.x;
  const int r0 = blockIdx.y * 32, c0 = blockIdx.x * 32;
  const int x = t & 31, y = t >> 5;  // y in 0..7
#pragma unroll
  for (int i = 0; i < 4; ++i)
    tile[y + i * 8][x] = in[(size_t)(r0 + y + i * 8) * 1024 + c0 + x];
  __syncthreads();
#pragma unroll
  for (int i = 0; i < 4; ++i) {
    float v = tile[x][y + i * 8];
    u16 h = bf16_rne(v);
    u16 l = bf16_rne(v - bf16_to_f(h));
    size_t o = (size_t)(c0 + y + i * 8) * 1024 + r0 + x;
    hiT[o] = h;
    loT[o] = l;
  }
}

// ---------- zero a 1024-float vector ----------
__global__ __launch_bounds__(256) void zero_vec(float* __restrict__ h) {
  h[blockIdx.x * 256 + threadIdx.x] = 0.f;
}

// ---------- h[d] += sum_{e in block} W[e][d] * b[e]  (64 blocks, atomics) ----------
__global__ __launch_bounds__(256) void colvec_kernel(const float* __restrict__ W,
                                                     const float* __restrict__ b,
                                                     float* __restrict__ h) {
  __shared__ float sb[16];
  const int t = threadIdx.x;
  const int e0 = blockIdx.x * 16;
  if (t < 16) sb[t] = b[e0 + t];
  __syncthreads();
  float a0 = 0.f, a1 = 0.f, a2 = 0.f, a3 = 0.f;
#pragma unroll
  for (int i = 0; i < 16; ++i) {
    const float* row = W + (size_t)(e0 + i) * 1024;
    const float be = sb[i];
    a0 += row[t] * be;
    a1 += row[t + 256] * be;
    a2 += row[t + 512] * be;
    a3 += row[t + 768] * be;
  }
  atomicAdd(&h[t], a0);
  atomicAdd(&h[t + 256], a1);
  atomicAdd(&h[t + 512], a2);
  atomicAdd(&h[t + 768], a3);
}

// ---------- legacy 128x128 B^T GEMM (kept for the tiny Mt product) ----------
template <int NPROD, int EPI>
__global__ __launch_bounds__(256) void gemm_bt(
    const u16* __restrict__ Ah, const u16* __restrict__ Al,
    const u16* __restrict__ Bh, const u16* __restrict__ Bl,
    const float* __restrict__ bias,
    u16* __restrict__ Ch, u16* __restrict__ Cl,
    float* __restrict__ Cf, float scale, int K,
    int lda, int ldb, int ldc,
    long long batchA, long long batchB, long long batchC) {
  __shared__ u16 sAh[4096];
  __shared__ u16 sBh[4096];
  __shared__ u16 sAl[NPROD == 3 ? 4096 : 64];
  __shared__ u16 sBl[NPROD == 3 ? 4096 : 64];

  const int t = threadIdx.x;
  const int w = t >> 6;
  const int lane = t & 63;
  const int m0 = blockIdx.y * 128;
  const int n0 = blockIdx.x * 128;
  const long long z = blockIdx.z;

  Ah += z * batchA;
  Bh += z * batchB;

  const int rS = t >> 2;
  const int cS = (((t & 3) ^ ((t >> 3) & 3))) * 8;
  const u16* pAh = Ah + (size_t)(m0 + rS) * lda + cS;
  const u16* pBh = Bh + (size_t)(n0 + rS) * ldb + cS;
  const u16* pAl = nullptr;
  const u16* pBl = nullptr;
  if constexpr (NPROD == 3) {
    pAl = Al + z * batchA + (size_t)(m0 + rS) * lda + cS;
    pBl = Bl + z * batchB + (size_t)(n0 + rS) * ldb + cS;
  }

  const int wr = (w >> 1) * 64;
  const int wc = (w & 1) * 64;
  const int fr = lane & 15;
  const int cc = lane >> 4;
  const int fk = (cc ^ ((fr >> 1) & 3)) * 8;

  f32x4 acc[4][4];
#pragma unroll
  for (int i = 0; i < 4; ++i)
#pragma unroll
    for (int j = 0; j < 4; ++j) acc[i][j] = (f32x4){0.f, 0.f, 0.f, 0.f};

  for (int k0 = 0; k0 < K; k0 += 32) {
    __syncthreads();
#pragma unroll
    for (int j = 0; j < 2; ++j) {
      gload16(pAh + (size_t)j * 64 * lda + k0, &sAh[j * 2048 + w * 512]);
      gload16(pBh + (size_t)j * 64 * ldb + k0, &sBh[j * 2048 + w * 512]);
      if constexpr (NPROD == 3) {
        gload16(pAl + (size_t)j * 64 * lda + k0, &sAl[j * 2048 + w * 512]);
        gload16(pBl + (size_t)j * 64 * ldb + k0, &sBl[j * 2048 + w * 512]);
      }
    }
    __syncthreads();
    bf16x8 ah[4], bh[4], al[4], bl[4];
#pragma unroll
    for (int i = 0; i < 4; ++i) {
      ah[i] = *(const bf16x8*)&sAh[(wr + i * 16 + fr) * 32 + fk];
      bh[i] = *(const bf16x8*)&sBh[(wc + i * 16 + fr) * 32 + fk];
      if constexpr (NPROD == 3) {
        al[i] = *(const bf16x8*)&sAl[(wr + i * 16 + fr) * 32 + fk];
        bl[i] = *(const bf16x8*)&sBl[(wc + i * 16 + fr) * 32 + fk];
      }
    }
#pragma unroll
    for (int i = 0; i < 4; ++i)
#pragma unroll
      for (int j = 0; j < 4; ++j) {
        acc[i][j] = __builtin_amdgcn_mfma_f32_16x16x32_bf16(ah[i], bh[j], acc[i][j], 0, 0, 0);
        if constexpr (NPROD == 3) {
          acc[i][j] = __builtin_amdgcn_mfma_f32_16x16x32_bf16(ah[i], bl[j], acc[i][j], 0, 0, 0);
          acc[i][j] = __builtin_amdgcn_mfma_f32_16x16x32_bf16(al[i], bh[j], acc[i][j], 0, 0, 0);
        }
      }
  }

  if constexpr (EPI >= 2) Cf += z * batchC;

#pragma unroll
  for (int i = 0; i < 4; ++i) {
    const int row0 = m0 + wr + i * 16 + ((lane >> 4) << 2);
#pragma unroll
    for (int j = 0; j < 4; ++j) {
      const int col = n0 + wc + j * 16 + (lane & 15);
      if constexpr (EPI == 0) {
        const float b = bias ? bias[col] : 0.0f;
#pragma unroll
        for (int r = 0; r < 4; ++r) {
          float c = acc[i][j][r] + b;
          u16 h = bf16_rne(c);
          u16 l = bf16_rne(c - bf16_to_f(h));
          size_t o = (size_t)(row0 + r) * ldc + col;
          Ch[o] = h;
          Cl[o] = l;
        }
      } else if constexpr (EPI == 1) {
        const float b = bias[col];
        ushort4 pk;
        pk.x = bf16_rne(acc[i][j][0] + b);
        pk.y = bf16_rne(acc[i][j][1] + b);
        pk.z = bf16_rne(acc[i][j][2] + b);
        pk.w = bf16_rne(acc[i][j][3] + b);
        const int bb = row0 >> 11;
        const int s = row0 & 2047;
        *(ushort4*)&Ch[(size_t)bb * 2097152 + (size_t)col * 2048 + s] = pk;
      } else if constexpr (EPI == 2) {
#pragma unroll
        for (int r = 0; r < 4; ++r)
          Cf[(size_t)(row0 + r) * ldc + col] = acc[i][j][r] * scale;
      } else {
        const float wv = bias[(size_t)z * 2048 + col];
#pragma unroll
        for (int r = 0; r < 4; ++r)
          Cf[(size_t)(row0 + r) * ldc + col] = (acc[i][j][r] + wv) * scale;
      }
    }
  }
}

// ---------- 256x256 counted-vmcnt B^T GEMM (round-9 best: 898 us) ----------
// Per K-tile: STAGE(next) -> vmcnt(8|4) counted (next tile's loads stay in
// flight; never drains to 0 in-loop) -> barrier A -> intra-wave counted-lgkm
// pipeline (each MFMA cluster overlaps next cluster's ds_reads) -> lgkm(0)
// -> barrier B. sched_barrier(0) pins (rule #18). setprio(1) around MFMAs.
// XCD-aware bijective blockIdx swizzle (FETCH 298->98MB measured).
template <int NPROD, int EPI>
__global__ __launch_bounds__(512) void gemm256(
    const u16* __restrict__ Ah, const u16* __restrict__ Al,
    const u16* __restrict__ Bh, const u16* __restrict__ Bl,
    const float* __restrict__ bias,
    u16* __restrict__ Ch, u16* __restrict__ Cl,
    float* __restrict__ Cf, float scale, int K,
    int lda, int ldb, int ldc,
    long long batchA, long long batchB, long long batchC) {
  __shared__ u16 sAh[2][8192];
  __shared__ u16 sBh[2][8192];
  __shared__ u16 sAl[NPROD == 3 ? 16384 : 8];
  __shared__ u16 sBl[NPROD == 3 ? 16384 : 8];

  const int t = threadIdx.x;
  const int w = t >> 6;     // wave 0..7
  const int lane = t & 63;

  // XCD-aware bijective swizzle (all gemm256 grids have total % 8 == 0)
  const u32 gx = gridDim.x;
  const u32 gxy = gridDim.x * gridDim.y;
  const u32 total = gxy * gridDim.z;
  const u32 h = blockIdx.x + gridDim.x * (blockIdx.y + gridDim.y * blockIdx.z);
  const u32 l = (h & 7) * (total >> 3) + (h >> 3);
  const u32 bz = l / gxy;
  const u32 rem = l - bz * gxy;
  const u32 by = rem / gx;
  const u32 bx = rem - by * gx;
  const int m0 = by * 256;
  const int n0 = bx * 256;
  const long long z = bz;

  const int rS = t >> 2;                            // 0..127 (staging row)
  const int cS = ((t & 3) ^ ((rS >> 1) & 3)) * 8;   // swizzled source chunk
  const u16* pAh = Ah + z * batchA + (size_t)(m0 + rS) * lda + cS;
  const u16* pBh = Bh + z * batchB + (size_t)(n0 + rS) * ldb + cS;
  const u16* pAl = nullptr;
  const u16* pBl = nullptr;
  if constexpr (NPROD == 3) {
    pAl = Al + z * batchA + (size_t)(m0 + rS) * lda + cS;
    pBl = Bl + z * batchB + (size_t)(n0 + rS) * ldb + cS;
  }

  const int wr = (w >> 2) * 128;  // wave row origin
  const int wc = (w & 3) * 64;    // wave col origin
  const int fr = lane & 15;
  const int fk = (((lane >> 4) ^ ((fr >> 1) & 3)) * 8);

  f32x4 acc[8][4];
#pragma unroll
  for (int i = 0; i < 8; ++i)
#pragma unroll
    for (int j = 0; j < 4; ++j) acc[i][j] = (f32x4){0.f, 0.f, 0.f, 0.f};

  auto SAH = [&](int b, int k0) {
    gload16(pAh + k0, &sAh[b][w * 512]);
    gload16(pAh + (size_t)128 * lda + k0, &sAh[b][4096 + w * 512]);
  };
  auto SBH = [&](int b, int k0) {
    gload16(pBh + k0, &sBh[b][w * 512]);
    gload16(pBh + (size_t)128 * ldb + k0, &sBh[b][4096 + w * 512]);
  };
  auto SAL = [&](int b, int k0) {
    gload16(pAl + k0, &sAl[b * 8192 + w * 512]);
    gload16(pAl + (size_t)128 * lda + k0, &sAl[b * 8192 + 4096 + w * 512]);
  };
  auto SBL = [&](int b, int k0) {
    gload16(pBl + k0, &sBl[b * 8192 + w * 512]);
    gload16(pBl + (size_t)128 * ldb + k0, &sBl[b * 8192 + 4096 + w * 512]);
  };

  // prologue: stage tile 0 only (drained by first in-loop counted vmcnt)
  SAH(0, 0);
  SBH(0, 0);
  if constexpr (NPROD == 3) {
    SAL(0, 0);
    SBL(0, 0);
  }

  const int nt = K >> 5;
  for (int kt = 0; kt < nt; ++kt) {
    const int cur = kt & 1;
    const int nxt = cur ^ 1;
    const bool pf = (kt + 1) < nt;

    if (pf) {
      const int kn = (kt + 1) << 5;
      SAH(nxt, kn);
      SBH(nxt, kn);
      if constexpr (NPROD == 3) {
        SAL(nxt, kn);
        SBL(nxt, kn);
      }
    }
    __builtin_amdgcn_sched_barrier(0);
    if (pf) {
      if constexpr (NPROD == 3)
        asm volatile("s_waitcnt vmcnt(8)" ::: "memory");
      else
        asm volatile("s_waitcnt vmcnt(4)" ::: "memory");
    } else {
      asm volatile("s_waitcnt vmcnt(0)" ::: "memory");
    }
    __builtin_amdgcn_sched_barrier(0);
    asm volatile("s_barrier" ::: "memory");  // barrier A: tile kt visible

    if constexpr (NPROD == 3) {
      bf16x8 bh[4], bl[4], a[4][4];
#pragma unroll
      for (int n = 0; n < 4; ++n) {
        bh[n] = *(const bf16x8*)&sBh[cur][(wc + n * 16 + fr) * 32 + fk];
        bl[n] = *(const bf16x8*)&sBl[cur * 8192 + (wc + n * 16 + fr) * 32 + fk];
      }
      a[0][0] = *(const bf16x8*)&sAh[cur][(wr + 0 * 16 + fr) * 32 + fk];
      a[0][1] = *(const bf16x8*)&sAh[cur][(wr + 1 * 16 + fr) * 32 + fk];
      a[0][2] = *(const bf16x8*)&sAl[cur * 8192 + (wr + 0 * 16 + fr) * 32 + fk];
      a[0][3] = *(const bf16x8*)&sAl[cur * 8192 + (wr + 1 * 16 + fr) * 32 + fk];
#pragma unroll
      for (int q = 0; q < 4; ++q) {
        if (q < 3) {
          a[q + 1][0] = *(const bf16x8*)&sAh[cur][(wr + (2 * q + 2) * 16 + fr) * 32 + fk];
          a[q + 1][1] = *(const bf16x8*)&sAh[cur][(wr + (2 * q + 3) * 16 + fr) * 32 + fk];
          a[q + 1][2] = *(const bf16x8*)&sAl[cur * 8192 + (wr + (2 * q + 2) * 16 + fr) * 32 + fk];
          a[q + 1][3] = *(const bf16x8*)&sAl[cur * 8192 + (wr + (2 * q + 3) * 16 + fr) * 32 + fk];
        }
        __builtin_amdgcn_sched_barrier(0);
        if (q < 3)
          asm volatile("s_waitcnt lgkmcnt(4)" ::: "memory");
        else
          asm volatile("s_waitcnt lgkmcnt(0)" ::: "memory");
        __builtin_amdgcn_sched_barrier(0);
        __builtin_amdgcn_s_setprio(1);
#pragma unroll
        for (int n = 0; n < 4; ++n) {
          acc[2 * q][n] = __builtin_amdgcn_mfma_f32_16x16x32_bf16(a[q][0], bh[n], acc[2 * q][n], 0, 0, 0);
          acc[2 * q + 1][n] = __builtin_amdgcn_mfma_f32_16x16x32_bf16(a[q][1], bh[n], acc[2 * q + 1][n], 0, 0, 0);
        }
#pragma unroll
        for (int n = 0; n < 4; ++n) {
          acc[2 * q][n] = __builtin_amdgcn_mfma_f32_16x16x32_bf16(a[q][0], bl[n], acc[2 * q][n], 0, 0, 0);
          acc[2 * q + 1][n] = __builtin_amdgcn_mfma_f32_16x16x32_bf16(a[q][1], bl[n], acc[2 * q + 1][n], 0, 0, 0);
        }
#pragma unroll
        for (int n = 0; n < 4; ++n) {
          acc[2 * q][n] = __builtin_amdgcn_mfma_f32_16x16x32_bf16(a[q][2], bh[n], acc[2 * q][n], 0, 0, 0);
          acc[2 * q + 1][n] = __builtin_amdgcn_mfma_f32_16x16x32_bf16(a[q][3], bh[n], acc[2 * q + 1][n], 0, 0, 0);
        }
        __builtin_amdgcn_s_setprio(0);
        __builtin_amdgcn_sched_barrier(0);
      }
    } else {
      bf16x8 bh[4], a[2][4];
#pragma unroll
      for (int n = 0; n < 4; ++n)
        bh[n] = *(const bf16x8*)&sBh[cur][(wc + n * 16 + fr) * 32 + fk];
#pragma unroll
      for (int i = 0; i < 4; ++i)
        a[0][i] = *(const bf16x8*)&sAh[cur][(wr + i * 16 + fr) * 32 + fk];
#pragma unroll
      for (int q = 0; q < 2; ++q) {
        if (q < 1) {
#pragma unroll
          for (int i = 0; i < 4; ++i)
            a[1][i] = *(const bf16x8*)&sAh[cur][(wr + (4 + i) * 16 + fr) * 32 + fk];
        }
        __builtin_amdgcn_sched_barrier(0);
        if (q < 1)
          asm volatile("s_waitcnt lgkmcnt(4)" ::: "memory");
        else
          asm volatile("s_waitcnt lgkmcnt(0)" ::: "memory");
        __builtin_amdgcn_sched_barrier(0);
        __builtin_amdgcn_s_setprio(1);
#pragma unroll
        for (int i = 0; i < 4; ++i)
#pragma unroll
          for (int n = 0; n < 4; ++n)
            acc[4 * q + i][n] = __builtin_amdgcn_mfma_f32_16x16x32_bf16(a[q][i], bh[n], acc[4 * q + i][n], 0, 0, 0);
        __builtin_amdgcn_s_setprio(0);
        __builtin_amdgcn_sched_barrier(0);
      }
    }

    asm volatile("s_waitcnt lgkmcnt(0)" ::: "memory");
    asm volatile("s_barrier" ::: "memory");  // barrier B: buffer reuse safe
  }

  if constexpr (EPI >= 2) Cf += z * batchC;

#pragma unroll
  for (int i = 0; i < 8; ++i) {
    const int row0 = m0 + wr + i * 16 + ((lane >> 4) << 2);
#pragma unroll
    for (int j = 0; j < 4; ++j) {
      const int col = n0 + wc + j * 16 + (lane & 15);
      if constexpr (EPI == 0) {
        const float bsv = bias ? bias[col] : 0.0f;
#pragma unroll
        for (int r = 0; r < 4; ++r) {
          float c = acc[i][j][r] + bsv;
          u16 hh = bf16_rne(c);
          u16 ll = bf16_rne(c - bf16_to_f(hh));
          size_t o = (size_t)(row0 + r) * ldc + col;
          Ch[o] = hh;
          Cl[o] = ll;
        }
      } else if constexpr (EPI == 1) {
        const float bsv = bias[col];
        ushort4 pk;
        pk.x = bf16_rne(acc[i][j][0] + bsv);
        pk.y = bf16_rne(acc[i][j][1] + bsv);
        pk.z = bf16_rne(acc[i][j][2] + bsv);
        pk.w = bf16_rne(acc[i][j][3] + bsv);
        const int bb = row0 >> 11;
        const int s = row0 & 2047;
        *(ushort4*)&Ch[(size_t)bb * 2097152 + (size_t)col * 2048 + s] = pk;
      } else if constexpr (EPI == 2) {
#pragma unroll
        for (int r = 0; r < 4; ++r)
          Cf[(size_t)(row0 + r) * ldc + col] = acc[i][j][r] * scale;
      } else {  // EPI == 3
        const float wv = bias[(size_t)z * 2048 + col];
#pragma unroll
        for (int r = 0; r < 4; ++r)
          Cf[(size_t)(row0 + r) * ldc + col] = (acc[i][j][r] + wv) * scale;
      }
    }
  }
}

// ---------- row softmax: in-place fp32 + bf16 copy ----------
__global__ __launch_bounds__(256) void softmax_kernel(float* __restrict__ L,
                                                      u16* __restrict__ P) {
  const size_t row = blockIdx.x;
  float* r = L + row * 2048;
  u16* p = P + row * 2048;
  const int t = threadIdx.x;
  const int w = t >> 6;
  const int lane = t & 63;

  float4 v0 = ((const float4*)r)[2 * t];
  float4 v1 = ((const float4*)r)[2 * t + 1];
  float e[8] = {v0.x, v0.y, v0.z, v0.w, v1.x, v1.y, v1.z, v1.w};

  float vm = e[0];
#pragma unroll
  for (int j = 1; j < 8; ++j) vm = fmaxf(vm, e[j]);
#pragma unroll
  for (int o = 32; o > 0; o >>= 1) vm = fmaxf(vm, __shfl_xor(vm, o, 64));
  __shared__ float redm[4], reds[4];
  if (lane == 0) redm[w] = vm;
  __syncthreads();
  vm = fmaxf(fmaxf(redm[0], redm[1]), fmaxf(redm[2], redm[3]));

  float s = 0.f;
#pragma unroll
  for (int j = 0; j < 8; ++j) {
    e[j] = __expf(e[j] - vm);
    s += e[j];
  }
#pragma unroll
  for (int o = 32; o > 0; o >>= 1) s += __shfl_xor(s, o, 64);
  if (lane == 0) reds[w] = s;
  __syncthreads();
  s = reds[0] + reds[1] + reds[2] + reds[3];
  const float inv = 1.0f / s;

  float4 o0, o1;
  o0.x = e[0] * inv; o0.y = e[1] * inv; o0.z = e[2] * inv; o0.w = e[3] * inv;
  o1.x = e[4] * inv; o1.y = e[5] * inv; o1.z = e[6] * inv; o1.w = e[7] * inv;
  ((float4*)r)[2 * t] = o0;
  ((float4*)r)[2 * t + 1] = o1;
  union { u16 u[8]; uint4 q; } pk;
  pk.u[0] = bf16_rne(o0.x); pk.u[1] = bf16_rne(o0.y);
  pk.u[2] = bf16_rne(o0.z); pk.u[3] = bf16_rne(o0.w);
  pk.u[4] = bf16_rne(o1.x); pk.u[5] = bf16_rne(o1.y);
  pk.u[6] = bf16_rne(o1.z); pk.u[7] = bf16_rne(o1.w);
  ((uint4*)p)[t] = pk.q;
}

extern "C" void kernel_launch(void* const* d_in, const int* in_sizes, int n_in,
                              void* d_out, int out_size, void* d_ws, size_t ws_size,
                              hipStream_t stream) {
  const float* Xq = (const float*)d_in[0];
  const float* Xk = (const float*)d_in[1];
  const float* Xv = (const float*)d_in[2];
  const float* Wq = (const float*)d_in[3];
  const float* bq = (const float*)d_in[4];
  const float* Wk = (const float*)d_in[5];
  const float* bk = (const float*)d_in[6];  // unused: row-constant in logits, softmax-invariant
  const float* Wv = (const float*)d_in[7];
  const float* bv = (const float*)d_in[8];
  (void)bk;

  char* out = (char*)d_out;
  char* ws = (char*)d_ws;

  u16* T_hi = (u16*)(out + 0);
  u16* T_lo = (u16*)(out + 33554432);
  u16* Xq_hi = (u16*)(out + 67108864);
  u16* Xq_lo = (u16*)(out + 100663296);
  u16* Xv_hi = (u16*)(out + 134217728);
  u16* Mt_hi = (u16*)(out + 167772160);
  u16* Mt_lo = (u16*)(out + 171966464);
  float* logits = (float*)(out + 67108864);
  float* outO = (float*)(out + 0);

  u16* WqT_hi = (u16*)(ws + 0);
  u16* WqT_lo = (u16*)(ws + 2097152);
  u16* WkT_hi = (u16*)(ws + 4194304);
  u16* WkT_lo = (u16*)(ws + 6291456);
  u16* Wv_hi = (u16*)(ws + 8388608);
  u16* P = (u16*)(ws + 0);
  float* hvec = (float*)(ws + 67108864);
  float* wvec = (float*)(ws + 67112960);
  u16* Xk_hi = (u16*)(ws + 67178496);
  u16* Xk_lo = (u16*)(ws + 100732928);
  u16* Vt = (u16*)(ws + 134287360);

  // 1) weight transforms (merged transposes; h = Wk^T bq)
  transpose_split2<<<dim3(32, 32, 2), 256, 0, stream>>>(
      Wq, WqT_hi, WqT_lo, Wk, WkT_hi, WkT_lo);
  zero_vec<<<4, 256, 0, stream>>>(hvec);
  colvec_kernel<<<64, 256, 0, stream>>>(Wk, bq, hvec);
  split_kernel<<<512, 256, 0, stream>>>(Wv, Wv_hi, nullptr, 131072);

  // 2) input splits: Xk fused with w = Xk h; Xq+Xv merged
  splitk_rowdot<<<4096, 256, 0, stream>>>(Xk, hvec, Xk_hi, Xk_lo, wvec);
  split2_kernel<<<dim3(8192, 1, 2), 256, 0, stream>>>(
      Xq, Xq_hi, Xq_lo, Xv, Xv_hi);

  // 3) Mt = Wk^T Wq (tiny; legacy kernel)
  gemm_bt<3, 0><<<dim3(8, 8, 1), 256, 0, stream>>>(
      WkT_hi, WkT_lo, WqT_hi, WqT_lo, nullptr, Mt_hi, Mt_lo, nullptr, 1.f,
      1024, 1024, 1024, 1024, 0, 0, 0);
  // 4) v = Xv @ Wv^T + bv -> Vt[b][d][s]
  gemm256<1, 1><<<dim3(4, 64, 1), 512, 0, stream>>>(
      Xv_hi, nullptr, Wv_hi, nullptr, bv, Vt, nullptr, nullptr, 1.f,
      1024, 1024, 1024, 1024, 0, 0, 0);
  // 5) T = Xq @ M -> hi/lo in d_out[0,64M)
  gemm256<3, 0><<<dim3(4, 64, 1), 512, 0, stream>>>(
      Xq_hi, Xq_lo, Mt_hi, Mt_lo, nullptr, T_hi, T_lo, nullptr, 1.f,
      1024, 1024, 1024, 1024, 0, 0, 0);
  // 6) logits = 10*(T @ Xk^T + w_j) per batch
  gemm256<3, 3><<<dim3(8, 8, 8), 512, 0, stream>>>(
      T_hi, T_lo, Xk_hi, Xk_lo, wvec, nullptr, nullptr, logits, 10.f,
      1024, 1024, 1024, 2048, 2048LL * 1024, 2048LL * 1024, 2048LL * 2048);
  // 7) softmax in-place, bf16 copy to P
  softmax_kernel<<<16384, 256, 0, stream>>>(logits, P);
  // 8) out = P @ V per batch
  gemm256<1, 2><<<dim3(4, 8, 8), 512, 0, stream>>>(
      P, nullptr, Vt, nullptr, nullptr, nullptr, nullptr, outO, 1.f,
      2048, 2048, 2048, 1024, 2048LL * 2048, 1024LL * 2048, 2048LL * 1024);
}

// Round 18
// 845.141 us; speedup vs baseline: 1.1290x; 1.0314x over previous
//
#include <hip/hip_runtime.h>

typedef unsigned short u16;
typedef unsigned int u32;
typedef __bf16 bf16x8 __attribute__((ext_vector_type(8)));
typedef float f32x4 __attribute__((ext_vector_type(4)));

// ---------- helpers ----------
__device__ __forceinline__ u16 bf16_rne(float f) {
  u32 u = __float_as_uint(f);
  u += 0x7fffu + ((u >> 16) & 1u);
  return (u16)(u >> 16);
}
__device__ __forceinline__ float bf16_to_f(u16 h) {
  return __uint_as_float(((u32)h) << 16);
}
__device__ __forceinline__ void gload16(const u16* g, u16* l) {
  __builtin_amdgcn_global_load_lds(
      (const __attribute__((address_space(1))) void*)g,
      (__attribute__((address_space(3))) void*)l, 16, 0, 0);
}

// ---------- split fp32 -> bf16 hi (+ optional lo residual) ----------
__global__ __launch_bounds__(256) void split_kernel(const float* __restrict__ x,
                                                    u16* __restrict__ hi,
                                                    u16* __restrict__ lo, int n8) {
  int i = blockIdx.x * 256 + threadIdx.x;
  if (i >= n8) return;
  float4 a = ((const float4*)x)[2 * i];
  float4 b = ((const float4*)x)[2 * i + 1];
  float v[8] = {a.x, a.y, a.z, a.w, b.x, b.y, b.z, b.w};
  union { u16 u[8]; uint4 q; } H, L;
#pragma unroll
  for (int j = 0; j < 8; ++j) H.u[j] = bf16_rne(v[j]);
  ((uint4*)hi)[i] = H.q;
  if (lo != nullptr) {
#pragma unroll
    for (int j = 0; j < 8; ++j) L.u[j] = bf16_rne(v[j] - bf16_to_f(H.u[j]));
    ((uint4*)lo)[i] = L.q;
  }
}

// ---------- merged split for Xq (hi+lo) and Xv (hi only) ----------
__global__ __launch_bounds__(256) void split2_kernel(const float* __restrict__ x0,
                                                     u16* __restrict__ hi0,
                                                     u16* __restrict__ lo0,
                                                     const float* __restrict__ x1,
                                                     u16* __restrict__ hi1) {
  int i = blockIdx.x * 256 + threadIdx.x;
  const float* x = blockIdx.z ? x1 : x0;
  u16* hi = blockIdx.z ? hi1 : hi0;
  float4 a = ((const float4*)x)[2 * i];
  float4 b = ((const float4*)x)[2 * i + 1];
  float v[8] = {a.x, a.y, a.z, a.w, b.x, b.y, b.z, b.w};
  union { u16 u[8]; uint4 q; } H, L;
#pragma unroll
  for (int j = 0; j < 8; ++j) H.u[j] = bf16_rne(v[j]);
  ((uint4*)hi)[i] = H.q;
  if (blockIdx.z == 0) {
#pragma unroll
    for (int j = 0; j < 8; ++j) L.u[j] = bf16_rne(v[j] - bf16_to_f(H.u[j]));
    ((uint4*)lo0)[i] = L.q;
  }
}

// ---------- fused Xk split (hi/lo) + w[row] = Xk[row,:].h  ----------
__global__ __launch_bounds__(256) void splitk_rowdot(const float* __restrict__ X,
                                                     const float* __restrict__ h,
                                                     u16* __restrict__ hi,
                                                     u16* __restrict__ lo,
                                                     float* __restrict__ w) {
  const int t = threadIdx.x, lane = t & 63, wv = t >> 6;
  const size_t row = (size_t)blockIdx.x * 4 + wv;
  const float* xr = X + row * 1024;
  const float4* hf = (const float4*)h;
  float acc = 0.f;
#pragma unroll
  for (int half = 0; half < 2; ++half) {
    const int e0 = half * 512 + lane * 8;
    float4 a = *(const float4*)&xr[e0];
    float4 b = *(const float4*)&xr[e0 + 4];
    float4 ha = hf[e0 >> 2];
    float4 hb = hf[(e0 >> 2) + 1];
    acc += a.x * ha.x + a.y * ha.y + a.z * ha.z + a.w * ha.w +
           b.x * hb.x + b.y * hb.y + b.z * hb.z + b.w * hb.w;
    float v[8] = {a.x, a.y, a.z, a.w, b.x, b.y, b.z, b.w};
    union { u16 u[8]; uint4 q; } H, L;
#pragma unroll
    for (int j = 0; j < 8; ++j) {
      H.u[j] = bf16_rne(v[j]);
      L.u[j] = bf16_rne(v[j] - bf16_to_f(H.u[j]));
    }
    const size_t ci = (row * 1024 + e0) >> 3;
    ((uint4*)hi)[ci] = H.q;
    ((uint4*)lo)[ci] = L.q;
  }
#pragma unroll
  for (int o = 32; o > 0; o >>= 1) acc += __shfl_xor(acc, o, 64);
  if (lane == 0) w[row] = acc;
}

// ---------- merged transpose 1024x1024 fp32 -> transposed bf16 hi/lo (x2) --
__global__ __launch_bounds__(256) void transpose_split2(
    const float* __restrict__ in0, u16* __restrict__ hiT0, u16* __restrict__ loT0,
    const float* __restrict__ in1, u16* __restrict__ hiT1, u16* __restrict__ loT1) {
  __shared__ float tile[32][33];
  const float* in = blockIdx.z ? in1 : in0;
  u16* hiT = blockIdx.z ? hiT1 : hiT0;
  u16* loT = blockIdx.z ? loT1 : loT0;
  const int t = threadIdx.x;
  const int r0 = blockIdx.y * 32, c0 = blockIdx.x * 32;
  const int x = t & 31, y = t >> 5;  // y in 0..7
#pragma unroll
  for (int i = 0; i < 4; ++i)
    tile[y + i * 8][x] = in[(size_t)(r0 + y + i * 8) * 1024 + c0 + x];
  __syncthreads();
#pragma unroll
  for (int i = 0; i < 4; ++i) {
    float v = tile[x][y + i * 8];
    u16 h = bf16_rne(v);
    u16 l = bf16_rne(v - bf16_to_f(h));
    size_t o = (size_t)(c0 + y + i * 8) * 1024 + r0 + x;
    hiT[o] = h;
    loT[o] = l;
  }
}

// ---------- zero a 1024-float vector ----------
__global__ __launch_bounds__(256) void zero_vec(float* __restrict__ h) {
  h[blockIdx.x * 256 + threadIdx.x] = 0.f;
}

// ---------- h[d] += sum_{e in block} W[e][d] * b[e]  (64 blocks, atomics) ----------
__global__ __launch_bounds__(256) void colvec_kernel(const float* __restrict__ W,
                                                     const float* __restrict__ b,
                                                     float* __restrict__ h) {
  __shared__ float sb[16];
  const int t = threadIdx.x;
  const int e0 = blockIdx.x * 16;
  if (t < 16) sb[t] = b[e0 + t];
  __syncthreads();
  float a0 = 0.f, a1 = 0.f, a2 = 0.f, a3 = 0.f;
#pragma unroll
  for (int i = 0; i < 16; ++i) {
    const float* row = W + (size_t)(e0 + i) * 1024;
    const float be = sb[i];
    a0 += row[t] * be;
    a1 += row[t + 256] * be;
    a2 += row[t + 512] * be;
    a3 += row[t + 768] * be;
  }
  atomicAdd(&h[t], a0);
  atomicAdd(&h[t + 256], a1);
  atomicAdd(&h[t + 512], a2);
  atomicAdd(&h[t + 768], a3);
}

// ---------- reduce 4 fp32 split-K partials -> bf16 hi/lo ----------
__global__ __launch_bounds__(256) void reduce4_split(const float* __restrict__ S,
                                                     u16* __restrict__ hi,
                                                     u16* __restrict__ lo) {
  const int i = blockIdx.x * 256 + threadIdx.x;  // float4 index (262144 total)
  float4 s0 = ((const float4*)S)[i];
  float4 s1 = ((const float4*)(S + 1048576))[i];
  float4 s2 = ((const float4*)(S + 2097152))[i];
  float4 s3 = ((const float4*)(S + 3145728))[i];
  float v[4] = {(s0.x + s1.x) + (s2.x + s3.x), (s0.y + s1.y) + (s2.y + s3.y),
                (s0.z + s1.z) + (s2.z + s3.z), (s0.w + s1.w) + (s2.w + s3.w)};
  union { u16 u[4]; ushort4 q; } H, L;
#pragma unroll
  for (int j = 0; j < 4; ++j) {
    H.u[j] = bf16_rne(v[j]);
    L.u[j] = bf16_rne(v[j] - bf16_to_f(H.u[j]));
  }
  ((ushort4*)hi)[i] = H.q;
  ((ushort4*)lo)[i] = L.q;
}

// ---------- legacy 128x128 B^T GEMM (Mt split-K partials via EPI=2) ----------
template <int NPROD, int EPI>
__global__ __launch_bounds__(256) void gemm_bt(
    const u16* __restrict__ Ah, const u16* __restrict__ Al,
    const u16* __restrict__ Bh, const u16* __restrict__ Bl,
    const float* __restrict__ bias,
    u16* __restrict__ Ch, u16* __restrict__ Cl,
    float* __restrict__ Cf, float scale, int K,
    int lda, int ldb, int ldc,
    long long batchA, long long batchB, long long batchC) {
  __shared__ u16 sAh[4096];
  __shared__ u16 sBh[4096];
  __shared__ u16 sAl[NPROD == 3 ? 4096 : 64];
  __shared__ u16 sBl[NPROD == 3 ? 4096 : 64];

  const int t = threadIdx.x;
  const int w = t >> 6;
  const int lane = t & 63;
  const int m0 = blockIdx.y * 128;
  const int n0 = blockIdx.x * 128;
  const long long z = blockIdx.z;

  Ah += z * batchA;
  Bh += z * batchB;

  const int rS = t >> 2;
  const int cS = (((t & 3) ^ ((t >> 3) & 3))) * 8;
  const u16* pAh = Ah + (size_t)(m0 + rS) * lda + cS;
  const u16* pBh = Bh + (size_t)(n0 + rS) * ldb + cS;
  const u16* pAl = nullptr;
  const u16* pBl = nullptr;
  if constexpr (NPROD == 3) {
    pAl = Al + z * batchA + (size_t)(m0 + rS) * lda + cS;
    pBl = Bl + z * batchB + (size_t)(n0 + rS) * ldb + cS;
  }

  const int wr = (w >> 1) * 64;
  const int wc = (w & 1) * 64;
  const int fr = lane & 15;
  const int cc = lane >> 4;
  const int fk = (cc ^ ((fr >> 1) & 3)) * 8;

  f32x4 acc[4][4];
#pragma unroll
  for (int i = 0; i < 4; ++i)
#pragma unroll
    for (int j = 0; j < 4; ++j) acc[i][j] = (f32x4){0.f, 0.f, 0.f, 0.f};

  for (int k0 = 0; k0 < K; k0 += 32) {
    __syncthreads();
#pragma unroll
    for (int j = 0; j < 2; ++j) {
      gload16(pAh + (size_t)j * 64 * lda + k0, &sAh[j * 2048 + w * 512]);
      gload16(pBh + (size_t)j * 64 * ldb + k0, &sBh[j * 2048 + w * 512]);
      if constexpr (NPROD == 3) {
        gload16(pAl + (size_t)j * 64 * lda + k0, &sAl[j * 2048 + w * 512]);
        gload16(pBl + (size_t)j * 64 * ldb + k0, &sBl[j * 2048 + w * 512]);
      }
    }
    __syncthreads();
    bf16x8 ah[4], bh[4], al[4], bl[4];
#pragma unroll
    for (int i = 0; i < 4; ++i) {
      ah[i] = *(const bf16x8*)&sAh[(wr + i * 16 + fr) * 32 + fk];
      bh[i] = *(const bf16x8*)&sBh[(wc + i * 16 + fr) * 32 + fk];
      if constexpr (NPROD == 3) {
        al[i] = *(const bf16x8*)&sAl[(wr + i * 16 + fr) * 32 + fk];
        bl[i] = *(const bf16x8*)&sBl[(wc + i * 16 + fr) * 32 + fk];
      }
    }
#pragma unroll
    for (int i = 0; i < 4; ++i)
#pragma unroll
      for (int j = 0; j < 4; ++j) {
        acc[i][j] = __builtin_amdgcn_mfma_f32_16x16x32_bf16(ah[i], bh[j], acc[i][j], 0, 0, 0);
        if constexpr (NPROD == 3) {
          acc[i][j] = __builtin_amdgcn_mfma_f32_16x16x32_bf16(ah[i], bl[j], acc[i][j], 0, 0, 0);
          acc[i][j] = __builtin_amdgcn_mfma_f32_16x16x32_bf16(al[i], bh[j], acc[i][j], 0, 0, 0);
        }
      }
  }

  if constexpr (EPI >= 2) Cf += z * batchC;

#pragma unroll
  for (int i = 0; i < 4; ++i) {
    const int row0 = m0 + wr + i * 16 + ((lane >> 4) << 2);
#pragma unroll
    for (int j = 0; j < 4; ++j) {
      const int col = n0 + wc + j * 16 + (lane & 15);
      if constexpr (EPI == 0) {
        const float b = bias ? bias[col] : 0.0f;
#pragma unroll
        for (int r = 0; r < 4; ++r) {
          float c = acc[i][j][r] + b;
          u16 h = bf16_rne(c);
          u16 l = bf16_rne(c - bf16_to_f(h));
          size_t o = (size_t)(row0 + r) * ldc + col;
          Ch[o] = h;
          Cl[o] = l;
        }
      } else if constexpr (EPI == 1) {
        const float b = bias[col];
        ushort4 pk;
        pk.x = bf16_rne(acc[i][j][0] + b);
        pk.y = bf16_rne(acc[i][j][1] + b);
        pk.z = bf16_rne(acc[i][j][2] + b);
        pk.w = bf16_rne(acc[i][j][3] + b);
        const int bb = row0 >> 11;
        const int s = row0 & 2047;
        *(ushort4*)&Ch[(size_t)bb * 2097152 + (size_t)col * 2048 + s] = pk;
      } else if constexpr (EPI == 2) {
#pragma unroll
        for (int r = 0; r < 4; ++r)
          Cf[(size_t)(row0 + r) * ldc + col] = acc[i][j][r] * scale;
      } else {
        const float wv = bias[(size_t)z * 2048 + col];
#pragma unroll
        for (int r = 0; r < 4; ++r)
          Cf[(size_t)(row0 + r) * ldc + col] = (acc[i][j][r] + wv) * scale;
      }
    }
  }
}

// ---------- 256x256 counted-vmcnt B^T GEMM ----------
// NPROD=3: BK=32 (round-9 measured-best path, unchanged).
// NPROD=1: BK=64 -- same skeleton, barrier pair per 64-K (halved overhead);
//   LDS 2 arrays x 32KB x dbuf = 128KB; 3-bit XOR swizzle (chunk^((row>>1)&7))
//   applied on both staging-source and read (involution); kc ascending keeps
//   bit-identical accumulation order.
template <int NPROD, int EPI>
__global__ __launch_bounds__(512) void gemm256(
    const u16* __restrict__ Ah, const u16* __restrict__ Al,
    const u16* __restrict__ Bh, const u16* __restrict__ Bl,
    const float* __restrict__ bias,
    u16* __restrict__ Ch, u16* __restrict__ Cl,
    float* __restrict__ Cf, float scale, int K,
    int lda, int ldb, int ldc,
    long long batchA, long long batchB, long long batchC) {
  constexpr int TS = (NPROD == 3) ? 8192 : 16384;  // elems per buffer
  __shared__ u16 sAh[2 * TS];
  __shared__ u16 sBh[2 * TS];
  __shared__ u16 sAl[NPROD == 3 ? 16384 : 8];
  __shared__ u16 sBl[NPROD == 3 ? 16384 : 8];

  const int t = threadIdx.x;
  const int w = t >> 6;     // wave 0..7
  const int lane = t & 63;

  // XCD-aware bijective swizzle (all gemm256 grids have total % 8 == 0)
  const u32 gx = gridDim.x;
  const u32 gxy = gridDim.x * gridDim.y;
  const u32 total = gxy * gridDim.z;
  const u32 h = blockIdx.x + gridDim.x * (blockIdx.y + gridDim.y * blockIdx.z);
  const u32 l = (h & 7) * (total >> 3) + (h >> 3);
  const u32 bz = l / gxy;
  const u32 rem = l - bz * gxy;
  const u32 by = rem / gx;
  const u32 bx = rem - by * gx;
  const int m0 = by * 256;
  const int n0 = bx * 256;
  const long long z = bz;

  // staging source mapping (swizzled chunk)
  const int rS = (NPROD == 3) ? (t >> 2) : (t >> 3);
  const int cS = (NPROD == 3) ? (((t & 3) ^ ((rS >> 1) & 3)) * 8)
                              : (((t & 7) ^ ((rS >> 1) & 7)) * 8);
  const u16* pAh = Ah + z * batchA + (size_t)(m0 + rS) * lda + cS;
  const u16* pBh = Bh + z * batchB + (size_t)(n0 + rS) * ldb + cS;
  const u16* pAl = nullptr;
  const u16* pBl = nullptr;
  if constexpr (NPROD == 3) {
    pAl = Al + z * batchA + (size_t)(m0 + rS) * lda + cS;
    pBl = Bl + z * batchB + (size_t)(n0 + rS) * ldb + cS;
  }

  const int wr = (w >> 2) * 128;  // wave row origin
  const int wc = (w & 3) * 64;    // wave col origin
  const int fr = lane & 15;
  const int fk = (((lane >> 4) ^ ((fr >> 1) & 3)) * 8);      // BK=32 read swz
  const int fk0 = (((lane >> 4) ^ ((fr >> 1) & 7)) * 8);     // BK=64 kc=0
  const int fk1 = (((4 + (lane >> 4)) ^ ((fr >> 1) & 7)) * 8);  // BK=64 kc=1

  f32x4 acc[8][4];
#pragma unroll
  for (int i = 0; i < 8; ++i)
#pragma unroll
    for (int j = 0; j < 4; ++j) acc[i][j] = (f32x4){0.f, 0.f, 0.f, 0.f};

  // --- BK=32 staging (NPROD=3): 2 gloads per array per tile ---
  auto SAH = [&](int b, int k0) {
    gload16(pAh + k0, &sAh[b * TS + w * 512]);
    gload16(pAh + (size_t)128 * lda + k0, &sAh[b * TS + 4096 + w * 512]);
  };
  auto SBH = [&](int b, int k0) {
    gload16(pBh + k0, &sBh[b * TS + w * 512]);
    gload16(pBh + (size_t)128 * ldb + k0, &sBh[b * TS + 4096 + w * 512]);
  };
  auto SAL = [&](int b, int k0) {
    gload16(pAl + k0, &sAl[b * 8192 + w * 512]);
    gload16(pAl + (size_t)128 * lda + k0, &sAl[b * 8192 + 4096 + w * 512]);
  };
  auto SBL = [&](int b, int k0) {
    gload16(pBl + k0, &sBl[b * 8192 + w * 512]);
    gload16(pBl + (size_t)128 * ldb + k0, &sBl[b * 8192 + 4096 + w * 512]);
  };
  // --- BK=64 staging (NPROD=1): 4 gloads per array per tile ---
  auto SAH64 = [&](int b, int k0) {
#pragma unroll
    for (int j = 0; j < 4; ++j)
      gload16(pAh + (size_t)j * 64 * lda + k0, &sAh[b * TS + j * 4096 + w * 512]);
  };
  auto SBH64 = [&](int b, int k0) {
#pragma unroll
    for (int j = 0; j < 4; ++j)
      gload16(pBh + (size_t)j * 64 * ldb + k0, &sBh[b * TS + j * 4096 + w * 512]);
  };

  if constexpr (NPROD == 3) {
    // ---- BK=32 path: byte-identical to round-9/17 measured-best ----
    SAH(0, 0);
    SBH(0, 0);
    SAL(0, 0);
    SBL(0, 0);
    const int nt = K >> 5;
    for (int kt = 0; kt < nt; ++kt) {
      const int cur = kt & 1;
      const int nxt = cur ^ 1;
      const bool pf = (kt + 1) < nt;
      if (pf) {
        const int kn = (kt + 1) << 5;
        SAH(nxt, kn);
        SBH(nxt, kn);
        SAL(nxt, kn);
        SBL(nxt, kn);
      }
      __builtin_amdgcn_sched_barrier(0);
      if (pf)
        asm volatile("s_waitcnt vmcnt(8)" ::: "memory");
      else
        asm volatile("s_waitcnt vmcnt(0)" ::: "memory");
      __builtin_amdgcn_sched_barrier(0);
      asm volatile("s_barrier" ::: "memory");  // barrier A

      bf16x8 bh[4], bl[4], a[4][4];
#pragma unroll
      for (int n = 0; n < 4; ++n) {
        bh[n] = *(const bf16x8*)&sBh[cur * TS + (wc + n * 16 + fr) * 32 + fk];
        bl[n] = *(const bf16x8*)&sBl[cur * 8192 + (wc + n * 16 + fr) * 32 + fk];
      }
      a[0][0] = *(const bf16x8*)&sAh[cur * TS + (wr + 0 * 16 + fr) * 32 + fk];
      a[0][1] = *(const bf16x8*)&sAh[cur * TS + (wr + 1 * 16 + fr) * 32 + fk];
      a[0][2] = *(const bf16x8*)&sAl[cur * 8192 + (wr + 0 * 16 + fr) * 32 + fk];
      a[0][3] = *(const bf16x8*)&sAl[cur * 8192 + (wr + 1 * 16 + fr) * 32 + fk];
#pragma unroll
      for (int q = 0; q < 4; ++q) {
        if (q < 3) {
          a[q + 1][0] = *(const bf16x8*)&sAh[cur * TS + (wr + (2 * q + 2) * 16 + fr) * 32 + fk];
          a[q + 1][1] = *(const bf16x8*)&sAh[cur * TS + (wr + (2 * q + 3) * 16 + fr) * 32 + fk];
          a[q + 1][2] = *(const bf16x8*)&sAl[cur * 8192 + (wr + (2 * q + 2) * 16 + fr) * 32 + fk];
          a[q + 1][3] = *(const bf16x8*)&sAl[cur * 8192 + (wr + (2 * q + 3) * 16 + fr) * 32 + fk];
        }
        __builtin_amdgcn_sched_barrier(0);
        if (q < 3)
          asm volatile("s_waitcnt lgkmcnt(4)" ::: "memory");
        else
          asm volatile("s_waitcnt lgkmcnt(0)" ::: "memory");
        __builtin_amdgcn_sched_barrier(0);
        __builtin_amdgcn_s_setprio(1);
#pragma unroll
        for (int n = 0; n < 4; ++n) {
          acc[2 * q][n] = __builtin_amdgcn_mfma_f32_16x16x32_bf16(a[q][0], bh[n], acc[2 * q][n], 0, 0, 0);
          acc[2 * q + 1][n] = __builtin_amdgcn_mfma_f32_16x16x32_bf16(a[q][1], bh[n], acc[2 * q + 1][n], 0, 0, 0);
        }
#pragma unroll
        for (int n = 0; n < 4; ++n) {
          acc[2 * q][n] = __builtin_amdgcn_mfma_f32_16x16x32_bf16(a[q][0], bl[n], acc[2 * q][n], 0, 0, 0);
          acc[2 * q + 1][n] = __builtin_amdgcn_mfma_f32_16x16x32_bf16(a[q][1], bl[n], acc[2 * q + 1][n], 0, 0, 0);
        }
#pragma unroll
        for (int n = 0; n < 4; ++n) {
          acc[2 * q][n] = __builtin_amdgcn_mfma_f32_16x16x32_bf16(a[q][2], bh[n], acc[2 * q][n], 0, 0, 0);
          acc[2 * q + 1][n] = __builtin_amdgcn_mfma_f32_16x16x32_bf16(a[q][3], bh[n], acc[2 * q + 1][n], 0, 0, 0);
        }
        __builtin_amdgcn_s_setprio(0);
        __builtin_amdgcn_sched_barrier(0);
      }
      asm volatile("s_waitcnt lgkmcnt(0)" ::: "memory");
      asm volatile("s_barrier" ::: "memory");  // barrier B
    }
  } else {
    // ---- BK=64 path (NPROD=1) ----
    SAH64(0, 0);
    SBH64(0, 0);
    const int nt = K >> 6;
    for (int kt = 0; kt < nt; ++kt) {
      const int cur = kt & 1;
      const int nxt = cur ^ 1;
      const bool pf = (kt + 1) < nt;
      if (pf) {
        const int kn = (kt + 1) << 6;
        SAH64(nxt, kn);
        SBH64(nxt, kn);
      }
      __builtin_amdgcn_sched_barrier(0);
      if (pf)
        asm volatile("s_waitcnt vmcnt(8)" ::: "memory");
      else
        asm volatile("s_waitcnt vmcnt(0)" ::: "memory");
      __builtin_amdgcn_sched_barrier(0);
      asm volatile("s_barrier" ::: "memory");  // barrier A

      bf16x8 b0[4], b1[4], a0[8], a1[8];
#pragma unroll
      for (int n = 0; n < 4; ++n) {
        b0[n] = *(const bf16x8*)&sBh[cur * TS + (wc + n * 16 + fr) * 64 + fk0];
        b1[n] = *(const bf16x8*)&sBh[cur * TS + (wc + n * 16 + fr) * 64 + fk1];
      }
#pragma unroll
      for (int i = 0; i < 8; ++i)
        a0[i] = *(const bf16x8*)&sAh[cur * TS + (wr + i * 16 + fr) * 64 + fk0];
#pragma unroll
      for (int i = 0; i < 8; ++i)
        a1[i] = *(const bf16x8*)&sAh[cur * TS + (wr + i * 16 + fr) * 64 + fk1];
      __builtin_amdgcn_sched_barrier(0);
      asm volatile("s_waitcnt lgkmcnt(8)" ::: "memory");  // b0,b1,a0 done; a1 in flight
      __builtin_amdgcn_sched_barrier(0);
      __builtin_amdgcn_s_setprio(1);
#pragma unroll
      for (int i = 0; i < 8; ++i)
#pragma unroll
        for (int n = 0; n < 4; ++n)
          acc[i][n] = __builtin_amdgcn_mfma_f32_16x16x32_bf16(a0[i], b0[n], acc[i][n], 0, 0, 0);
      __builtin_amdgcn_s_setprio(0);
      __builtin_amdgcn_sched_barrier(0);
      asm volatile("s_waitcnt lgkmcnt(0)" ::: "memory");
      __builtin_amdgcn_sched_barrier(0);
      __builtin_amdgcn_s_setprio(1);
#pragma unroll
      for (int i = 0; i < 8; ++i)
#pragma unroll
        for (int n = 0; n < 4; ++n)
          acc[i][n] = __builtin_amdgcn_mfma_f32_16x16x32_bf16(a1[i], b1[n], acc[i][n], 0, 0, 0);
      __builtin_amdgcn_s_setprio(0);
      __builtin_amdgcn_sched_barrier(0);
      asm volatile("s_barrier" ::: "memory");  // barrier B (lgkm already 0)
    }
  }

  if constexpr (EPI >= 2) Cf += z * batchC;

#pragma unroll
  for (int i = 0; i < 8; ++i) {
    const int row0 = m0 + wr + i * 16 + ((lane >> 4) << 2);
#pragma unroll
    for (int j = 0; j < 4; ++j) {
      const int col = n0 + wc + j * 16 + (lane & 15);
      if constexpr (EPI == 0) {
        const float bsv = bias ? bias[col] : 0.0f;
#pragma unroll
        for (int r = 0; r < 4; ++r) {
          float c = acc[i][j][r] + bsv;
          u16 hh = bf16_rne(c);
          u16 ll = bf16_rne(c - bf16_to_f(hh));
          size_t o = (size_t)(row0 + r) * ldc + col;
          Ch[o] = hh;
          Cl[o] = ll;
        }
      } else if constexpr (EPI == 1) {
        const float bsv = bias[col];
        ushort4 pk;
        pk.x = bf16_rne(acc[i][j][0] + bsv);
        pk.y = bf16_rne(acc[i][j][1] + bsv);
        pk.z = bf16_rne(acc[i][j][2] + bsv);
        pk.w = bf16_rne(acc[i][j][3] + bsv);
        const int bb = row0 >> 11;
        const int s = row0 & 2047;
        *(ushort4*)&Ch[(size_t)bb * 2097152 + (size_t)col * 2048 + s] = pk;
      } else if constexpr (EPI == 2) {
#pragma unroll
        for (int r = 0; r < 4; ++r)
          Cf[(size_t)(row0 + r) * ldc + col] = acc[i][j][r] * scale;
      } else {  // EPI == 3
        const float wv = bias[(size_t)z * 2048 + col];
#pragma unroll
        for (int r = 0; r < 4; ++r)
          Cf[(size_t)(row0 + r) * ldc + col] = (acc[i][j][r] + wv) * scale;
      }
    }
  }
}

// ---------- row softmax: in-place fp32 + bf16 copy ----------
__global__ __launch_bounds__(256) void softmax_kernel(float* __restrict__ L,
                                                      u16* __restrict__ P) {
  const size_t row = blockIdx.x;
  float* r = L + row * 2048;
  u16* p = P + row * 2048;
  const int t = threadIdx.x;
  const int w = t >> 6;
  const int lane = t & 63;

  float4 v0 = ((const float4*)r)[2 * t];
  float4 v1 = ((const float4*)r)[2 * t + 1];
  float e[8] = {v0.x, v0.y, v0.z, v0.w, v1.x, v1.y, v1.z, v1.w};

  float vm = e[0];
#pragma unroll
  for (int j = 1; j < 8; ++j) vm = fmaxf(vm, e[j]);
#pragma unroll
  for (int o = 32; o > 0; o >>= 1) vm = fmaxf(vm, __shfl_xor(vm, o, 64));
  __shared__ float redm[4], reds[4];
  if (lane == 0) redm[w] = vm;
  __syncthreads();
  vm = fmaxf(fmaxf(redm[0], redm[1]), fmaxf(redm[2], redm[3]));

  float s = 0.f;
#pragma unroll
  for (int j = 0; j < 8; ++j) {
    e[j] = __expf(e[j] - vm);
    s += e[j];
  }
#pragma unroll
  for (int o = 32; o > 0; o >>= 1) s += __shfl_xor(s, o, 64);
  if (lane == 0) reds[w] = s;
  __syncthreads();
  s = reds[0] + reds[1] + reds[2] + reds[3];
  const float inv = 1.0f / s;

  float4 o0, o1;
  o0.x = e[0] * inv; o0.y = e[1] * inv; o0.z = e[2] * inv; o0.w = e[3] * inv;
  o1.x = e[4] * inv; o1.y = e[5] * inv; o1.z = e[6] * inv; o1.w = e[7] * inv;
  ((float4*)r)[2 * t] = o0;
  ((float4*)r)[2 * t + 1] = o1;
  union { u16 u[8]; uint4 q; } pk;
  pk.u[0] = bf16_rne(o0.x); pk.u[1] = bf16_rne(o0.y);
  pk.u[2] = bf16_rne(o0.z); pk.u[3] = bf16_rne(o0.w);
  pk.u[4] = bf16_rne(o1.x); pk.u[5] = bf16_rne(o1.y);
  pk.u[6] = bf16_rne(o1.z); pk.u[7] = bf16_rne(o1.w);
  ((uint4*)p)[t] = pk.q;
}

extern "C" void kernel_launch(void* const* d_in, const int* in_sizes, int n_in,
                              void* d_out, int out_size, void* d_ws, size_t ws_size,
                              hipStream_t stream) {
  const float* Xq = (const float*)d_in[0];
  const float* Xk = (const float*)d_in[1];
  const float* Xv = (const float*)d_in[2];
  const float* Wq = (const float*)d_in[3];
  const float* bq = (const float*)d_in[4];
  const float* Wk = (const float*)d_in[5];
  const float* bk = (const float*)d_in[6];  // unused: row-constant in logits, softmax-invariant
  const float* Wv = (const float*)d_in[7];
  const float* bv = (const float*)d_in[8];
  (void)bk;

  char* out = (char*)d_out;
  char* ws = (char*)d_ws;

  u16* T_hi = (u16*)(out + 0);
  u16* T_lo = (u16*)(out + 33554432);
  u16* Xq_hi = (u16*)(out + 67108864);
  u16* Xq_lo = (u16*)(out + 100663296);
  u16* Xv_hi = (u16*)(out + 134217728);
  u16* Mt_hi = (u16*)(out + 167772160);
  u16* Mt_lo = (u16*)(out + 171966464);
  float* logits = (float*)(out + 67108864);
  float* outO = (float*)(out + 0);

  u16* WqT_hi = (u16*)(ws + 0);
  u16* WqT_lo = (u16*)(ws + 2097152);
  u16* WkT_hi = (u16*)(ws + 4194304);
  u16* WkT_lo = (u16*)(ws + 6291456);
  u16* Wv_hi = (u16*)(ws + 8388608);
  float* MtS = (float*)(ws + 16777216);      // 16 MB split-K scratch (dead after reduce)
  u16* P = (u16*)(ws + 0);
  float* hvec = (float*)(ws + 67108864);
  float* wvec = (float*)(ws + 67112960);
  u16* Xk_hi = (u16*)(ws + 67178496);
  u16* Xk_lo = (u16*)(ws + 100732928);
  u16* Vt = (u16*)(ws + 134287360);

  // 1) weight transforms (merged transposes; h = Wk^T bq)
  transpose_split2<<<dim3(32, 32, 2), 256, 0, stream>>>(
      Wq, WqT_hi, WqT_lo, Wk, WkT_hi, WkT_lo);
  zero_vec<<<4, 256, 0, stream>>>(hvec);
  colvec_kernel<<<64, 256, 0, stream>>>(Wk, bq, hvec);
  split_kernel<<<512, 256, 0, stream>>>(Wv, Wv_hi, nullptr, 131072);

  // 2) input splits: Xk fused with w = Xk h; Xq+Xv merged
  splitk_rowdot<<<4096, 256, 0, stream>>>(Xk, hvec, Xk_hi, Xk_lo, wvec);
  split2_kernel<<<dim3(8192, 1, 2), 256, 0, stream>>>(
      Xq, Xq_hi, Xq_lo, Xv, Xv_hi);

  // 3) Mt = Wk^T Wq, split-K x4 (256 blocks) -> fp32 partials -> hi/lo
  gemm_bt<3, 2><<<dim3(8, 8, 4), 256, 0, stream>>>(
      WkT_hi, WkT_lo, WqT_hi, WqT_lo, nullptr, nullptr, nullptr, MtS, 1.f,
      256, 1024, 1024, 1024, 256, 256, 1048576LL);
  reduce4_split<<<1024, 256, 0, stream>>>(MtS, Mt_hi, Mt_lo);

  // 4) v = Xv @ Wv^T + bv -> Vt[b][d][s]   (BK=64 path)
  gemm256<1, 1><<<dim3(4, 64, 1), 512, 0, stream>>>(
      Xv_hi, nullptr, Wv_hi, nullptr, bv, Vt, nullptr, nullptr, 1.f,
      1024, 1024, 1024, 1024, 0, 0, 0);
  // 5) T = Xq @ M -> hi/lo in d_out[0,64M)  (BK=32 path, unchanged)
  gemm256<3, 0><<<dim3(4, 64, 1), 512, 0, stream>>>(
      Xq_hi, Xq_lo, Mt_hi, Mt_lo, nullptr, T_hi, T_lo, nullptr, 1.f,
      1024, 1024, 1024, 1024, 0, 0, 0);
  // 6) logits = 10*(T @ Xk^T + w_j) per batch (BK=32 path, unchanged)
  gemm256<3, 3><<<dim3(8, 8, 8), 512, 0, stream>>>(
      T_hi, T_lo, Xk_hi, Xk_lo, wvec, nullptr, nullptr, logits, 10.f,
      1024, 1024, 1024, 2048, 2048LL * 1024, 2048LL * 1024, 2048LL * 2048);
  // 7) softmax in-place, bf16 copy to P
  softmax_kernel<<<16384, 256, 0, stream>>>(logits, P);
  // 8) out = P @ V per batch (BK=64 path)
  gemm256<1, 2><<<dim3(4, 8, 8), 512, 0, stream>>>(
      P, nullptr, Vt, nullptr, nullptr, nullptr, nullptr, outO, 1.f,
      2048, 2048, 2048, 1024, 2048LL * 2048, 1024LL * 2048, 2048LL * 1024);
}